// Round 7
// baseline (184.583 us; speedup 1.0000x reference)
//
#include <hip/hip_runtime.h>

#define NPTS 4096
#define CDIM 256
#define C4DIM 64

typedef __bf16 bf16x8 __attribute__((ext_vector_type(8)));
typedef float  f32x4  __attribute__((ext_vector_type(4)));

__device__ __forceinline__ void async_cp16(const void* g, void* l) {
    __builtin_amdgcn_global_load_lds(
        (const __attribute__((address_space(1))) void*)g,
        (__attribute__((address_space(3))) void*)l, 16, 0, 0);
}

// ---------------------------------------------------------------------------
// W prep: fp32 -> bf16, rows [Wq(64) | Wk(64) | Wv(256)] = 384 x 256.
// Plain row-major bf16 (proj reads B-frags directly from global).
// ---------------------------------------------------------------------------
__global__ __launch_bounds__(256) void wprep_kernel(
    const float* __restrict__ Wq, const float* __restrict__ Wk,
    const float* __restrict__ Wv, __bf16* __restrict__ wsz)
{
    int idx = blockIdx.x * 256 + threadIdx.x;   // 0..24575
    int row = idx >> 6;                         // 0..383
    int l4  = idx & 63;                         // float4 index within row
    const float* src;
    if (row < 64)       src = Wq + (size_t)row * CDIM;
    else if (row < 128) src = Wk + (size_t)(row - 64) * CDIM;
    else                src = Wv + (size_t)(row - 128) * CDIM;
    float4 f = *(const float4*)&src[l4 * 4];
    union { __bf16 h[4]; uint2 u; } pk;
    pk.h[0] = (__bf16)f.x; pk.h[1] = (__bf16)f.y;
    pk.h[2] = (__bf16)f.z; pk.h[3] = (__bf16)f.w;
    *(uint2*)&wsz[(size_t)row * CDIM + l4 * 4] = pk.u;
}

// ---------------------------------------------------------------------------
// MFMA projection, round 7: grid (NPTS/64, 2, B) = 512 blocks (2/CU), 256 thr.
// blockIdx.y=0 -> {q, k, v0}; y=1 -> {v1, v2, v3}. Out tile: 64 o x 64 n each.
// NO staging LDS: A-frags (x^T, bf16) from 64 direct global scalar loads
// (L3-hot); W B-frags as direct global b128 loads from bf16 workspace
// (L2-resident, 192 KB). LDS only for the epilogue transpose (17.4 KB).
// ---------------------------------------------------------------------------
__global__ __launch_bounds__(256) void proj_kernel(
    const float* __restrict__ x,
    const float* __restrict__ bq, const float* __restrict__ bk,
    const float* __restrict__ bv, const __bf16* __restrict__ wsz,
    __bf16* __restrict__ qT, __bf16* __restrict__ kT, __bf16* __restrict__ vo)
{
    __shared__ float OT[64][68];   // 17408 B

    const int t    = threadIdx.x;
    const int w    = t >> 6;
    const int lane = t & 63;
    const int quad = lane >> 4;
    const int l16  = lane & 15;

    const int n0   = blockIdx.x * 64;
    const int half = blockIdx.y;
    const int b    = blockIdx.z;

    // ---- A-frags: af[kc], m = n-point 16w+l16, k = c = kc*32+quad*8+u
    bf16x8 af[8];
    const float* xb = x + (size_t)b * CDIM * NPTS + n0 + 16 * w + l16;
    #pragma unroll
    for (int kc = 0; kc < 8; kc++) {
        union { __bf16 h8[8]; bf16x8 v; } pk;
        #pragma unroll
        for (int u = 0; u < 8; u++)
            pk.h8[u] = (__bf16)xb[(size_t)(kc * 32 + quad * 8 + u) * NPTS];
        af[kc] = pk.v;
    }

    #pragma unroll
    for (int ti = 0; ti < 3; ti++) {
        const int ot = half * 3 + ti;            // 0..5: q,k,v0,v1,v2,v3
        const __bf16* Wt = wsz + (size_t)ot * 64 * CDIM;

        f32x4 acc[4];
        #pragma unroll
        for (int tc = 0; tc < 4; tc++) acc[tc] = (f32x4)(0.f);

        #pragma unroll
        for (int kc = 0; kc < 8; kc++) {
            bf16x8 bw[4];
            #pragma unroll
            for (int tc = 0; tc < 4; tc++)
                bw[tc] = *(const bf16x8*)&Wt[(size_t)(16 * tc + l16) * CDIM
                                             + kc * 32 + quad * 8];
            #pragma unroll
            for (int tc = 0; tc < 4; tc++)
                acc[tc] = __builtin_amdgcn_mfma_f32_16x16x32_bf16(
                    af[kc], bw[tc], acc[tc], 0, 0, 0);
        }

        if (ot < 2) {
            // q/k: OT[n][o] transpose -> bf16 [n][64] n-major stores
            const float* bias = ot ? bk : bq;
            __syncthreads();   // previous tile's OT reads done
            #pragma unroll
            for (int tc = 0; tc < 4; tc++) {
                float bs = bias[16 * tc + l16];
                #pragma unroll
                for (int r4 = 0; r4 < 4; r4++)
                    OT[16 * w + 4 * quad + r4][16 * tc + l16] = acc[tc][r4] + bs;
            }
            __syncthreads();
            __bf16* outp = (ot == 0 ? qT : kT) + (size_t)b * NPTS * C4DIM;
            int n = t >> 2, op = (t & 3) * 16;
            union { __bf16 h[16]; uint4 u[2]; } pk;
            #pragma unroll
            for (int u2 = 0; u2 < 16; u2++) pk.h[u2] = (__bf16)OT[n][op + u2];
            *(uint4*)&outp[(size_t)(n0 + n) * C4DIM + op]     = pk.u[0];
            *(uint4*)&outp[(size_t)(n0 + n) * C4DIM + op + 8] = pk.u[1];
        } else {
            // v: OT[o][n] -> bf16 [c][n] c-major stores
            const int vs = ot - 2;
            __syncthreads();
            #pragma unroll
            for (int tc = 0; tc < 4; tc++) {
                float bs = bv[vs * 64 + 16 * tc + l16];
                f32x4 v4 = acc[tc];
                v4[0] += bs; v4[1] += bs; v4[2] += bs; v4[3] += bs;
                *(f32x4*)&OT[16 * tc + l16][16 * w + 4 * quad] = v4;
            }
            __syncthreads();
            int cl = t >> 2, np = (t & 3) * 16;
            int ch = vs * 64 + cl;
            union { __bf16 h[16]; uint4 u[2]; } pk;
            #pragma unroll
            for (int u2 = 0; u2 < 16; u2++) pk.h[u2] = (__bf16)OT[cl][np + u2];
            __bf16* outp = vo + ((size_t)b * CDIM + ch) * NPTS + n0 + np;
            *(uint4*)&outp[0] = pk.u[0];
            *(uint4*)&outp[8] = pk.u[1];
        }
    }
}

// ---------------------------------------------------------------------------
// MFMA flash attention (UNCHANGED from round 6 — isolating the proj change).
// grid (NPTS/64, CDIM/128, B) = 512 blocks (2/CU), block 256 (4 waves).
// Wave (r = w>>1, jh = w&1): 32 q-rows x 32-j slice x 128 ch.
// ---------------------------------------------------------------------------
__global__ __launch_bounds__(256, 2) void attn_kernel(
    const __bf16* __restrict__ qT, const __bf16* __restrict__ kT,
    const __bf16* __restrict__ vin, const float* __restrict__ xin,
    const float* __restrict__ gptr, float* __restrict__ out)
{
    __shared__ __align__(16) unsigned char sm[58368];
    unsigned char* Kb = sm;                  // [2][64 rows][128 B]
    unsigned char* Vb = sm + 16384;          // [2][128 rows][128 B]
    auto Ps  = (__bf16 (*)[72])(sm + 49152); // [64][72] bf16 (144B rows, 16B-aligned)
    auto OTa = (float (*)[68])(sm);          // [128][68] fp32, epilogue overlay
    float* Lp = (float*)(sm + 34816);        // [64] l-partials

    const int t    = threadIdx.x;
    const int w    = t >> 6;
    const int lane = t & 63;
    const int quad = lane >> 4;
    const int l16  = lane & 15;
    const int r    = w >> 1;    // row half
    const int jh   = w & 1;     // j half

    const int b  = blockIdx.z;
    const int i0 = blockIdx.x * 64;
    const int c0 = blockIdx.y * 128;

    const __bf16* qb = qT  + (size_t)b * NPTS * C4DIM;
    const __bf16* kb = kT  + (size_t)b * NPTS * C4DIM;
    const __bf16* vb = vin + (size_t)b * CDIM * NPTS;

    const int swz = (lane & 7) ^ ((lane >> 3) & 7);
    int koff[2], voff[4];
    #pragma unroll
    for (int s = 0; s < 2; s++) {
        int row = (2 * w + s) * 8 + (lane >> 3);
        koff[s] = row * 128 + swz * 16;
    }
    #pragma unroll
    for (int s = 0; s < 4; s++) {
        int row = (4 * w + s) * 8 + (lane >> 3);
        voff[s] = (c0 + row) * (NPTS * 2) + swz * 16;
    }

    bf16x8 aq[2][2];
    #pragma unroll
    for (int rt = 0; rt < 2; rt++)
        #pragma unroll
        for (int kc = 0; kc < 2; kc++)
            aq[rt][kc] = *(const bf16x8*)&qb[(size_t)(i0 + 32 * r + 16 * rt + l16) * C4DIM
                                             + kc * 32 + quad * 8];

    bf16x8 vone;
    #pragma unroll
    for (int u = 0; u < 8; u++) vone[u] = (__bf16)1.0f;

    f32x4 O[2][8], lacc[2];
    #pragma unroll
    for (int rt = 0; rt < 2; rt++) {
        lacc[rt] = (f32x4)(0.f);
        #pragma unroll
        for (int tc = 0; tc < 8; tc++) O[rt][tc] = (f32x4)(0.f);
    }

    {
        const char* kbase = (const char*)kb;
        const char* vbase = (const char*)vb;
        #pragma unroll
        for (int s = 0; s < 2; s++) async_cp16(kbase + koff[s], Kb + (2 * w + s) * 1024);
        #pragma unroll
        for (int s = 0; s < 4; s++) async_cp16(vbase + voff[s], Vb + (4 * w + s) * 1024);
    }

    int p = 0;
    for (int j0 = 0; j0 < NPTS; j0 += 64, p ^= 1) {
        __syncthreads();   // drains DMA into buf p; buf p^1 reads done

        if (j0 + 64 < NPTS) {
            const char* kbase = (const char*)kb + (size_t)(j0 + 64) * (C4DIM * 2);
            const char* vbase = (const char*)vb + (size_t)(j0 + 64) * 2;
            unsigned char* Kd = Kb + (p ^ 1) * 8192;
            unsigned char* Vd = Vb + (p ^ 1) * 16384;
            #pragma unroll
            for (int s = 0; s < 2; s++) async_cp16(kbase + koff[s], Kd + (2 * w + s) * 1024);
            #pragma unroll
            for (int s = 0; s < 4; s++) async_cp16(vbase + voff[s], Vd + (4 * w + s) * 1024);
        }

        const unsigned char* K = Kb + p * 8192;
        const unsigned char* V = Vb + p * 16384;

        f32x4 S[2][2];
        #pragma unroll
        for (int rt = 0; rt < 2; rt++)
            #pragma unroll
            for (int ct = 0; ct < 2; ct++) S[rt][ct] = (f32x4)(0.f);
        #pragma unroll
        for (int kc = 0; kc < 2; kc++) {
            bf16x8 bk2[2];
            #pragma unroll
            for (int ct = 0; ct < 2; ct++) {
                int row = 32 * jh + 16 * ct + l16;
                int slot = (kc * 4 + quad) ^ (l16 & 7);
                bk2[ct] = *(const bf16x8*)(K + row * 128 + slot * 16);
            }
            #pragma unroll
            for (int rt = 0; rt < 2; rt++)
                #pragma unroll
                for (int ct = 0; ct < 2; ct++)
                    S[rt][ct] = __builtin_amdgcn_mfma_f32_16x16x32_bf16(
                        aq[rt][kc], bk2[ct], S[rt][ct], 0, 0, 0);
        }

        #pragma unroll
        for (int rt = 0; rt < 2; rt++)
            #pragma unroll
            for (int ct = 0; ct < 2; ct++)
                #pragma unroll
                for (int r4 = 0; r4 < 4; r4++)
                    Ps[32 * r + 16 * rt + 4 * quad + r4][32 * jh + 16 * ct + l16] =
                        (__bf16)__expf(S[rt][ct][r4] - 32.0f);

        bf16x8 ap[2];
        #pragma unroll
        for (int rt = 0; rt < 2; rt++)
            ap[rt] = *(const bf16x8*)((const char*)&Ps[32 * r + 16 * rt + l16][0]
                                      + jh * 64 + quad * 16);
        #pragma unroll
        for (int tc = 0; tc < 8; tc++) {
            int row = 16 * tc + l16;
            int slot = (jh * 4 + quad) ^ (l16 & 7);
            bf16x8 bv2 = *(const bf16x8*)(V + row * 128 + slot * 16);
            #pragma unroll
            for (int rt = 0; rt < 2; rt++)
                O[rt][tc] = __builtin_amdgcn_mfma_f32_16x16x32_bf16(
                    ap[rt], bv2, O[rt][tc], 0, 0, 0);
        }
        #pragma unroll
        for (int rt = 0; rt < 2; rt++)
            lacc[rt] = __builtin_amdgcn_mfma_f32_16x16x32_bf16(ap[rt], vone, lacc[rt], 0, 0, 0);
    }

    __syncthreads();
    const float g = gptr[0];

    if (jh == 1) {
        float* dst = (float*)(sm + (size_t)(r * 64 + lane) * 272);
        #pragma unroll
        for (int rt = 0; rt < 2; rt++)
            #pragma unroll
            for (int tc = 0; tc < 8; tc++)
                *(f32x4*)(dst + (rt * 8 + tc) * 4) = O[rt][tc];
        if (l16 == 0) {
            #pragma unroll
            for (int rt = 0; rt < 2; rt++)
                #pragma unroll
                for (int r4 = 0; r4 < 4; r4++)
                    Lp[32 * r + 16 * rt + 4 * quad + r4] = lacc[rt][r4];
        }
    }
    __syncthreads();

    float inv[2][4];
    if (jh == 0) {
        const float* src = (const float*)(sm + (size_t)(r * 64 + lane) * 272);
        #pragma unroll
        for (int rt = 0; rt < 2; rt++)
            #pragma unroll
            for (int tc = 0; tc < 8; tc++)
                O[rt][tc] += *(const f32x4*)(src + (rt * 8 + tc) * 4);
        #pragma unroll
        for (int rt = 0; rt < 2; rt++)
            #pragma unroll
            for (int r4 = 0; r4 < 4; r4++) {
                float ls = lacc[rt][r4] + Lp[32 * r + 16 * rt + 4 * quad + r4];
                inv[rt][r4] = g / ls;
            }
    }
    __syncthreads();

    if (jh == 0) {
        #pragma unroll
        for (int rt = 0; rt < 2; rt++)
            #pragma unroll
            for (int tc = 0; tc < 8; tc++) {
                int c = 16 * tc + l16;
                float4 f;
                f.x = O[rt][tc][0] * inv[rt][0];
                f.y = O[rt][tc][1] * inv[rt][1];
                f.z = O[rt][tc][2] * inv[rt][2];
                f.w = O[rt][tc][3] * inv[rt][3];
                *(float4*)&OTa[c][32 * r + 16 * rt + 4 * quad] = f;
            }
    }
    __syncthreads();

    const float* xb = xin + (size_t)b * CDIM * NPTS;
    float*       ob = out + (size_t)b * CDIM * NPTS;
    #pragma unroll
    for (int s = 0; s < 8; s++) {
        int lin = t + 256 * s;
        int c = lin >> 4, col = (lin & 15) * 4;
        size_t gi = (size_t)(c0 + c) * NPTS + i0 + col;
        float4 ov = *(const float4*)&OTa[c][col];
        float4 xv = *(const float4*)&xb[gi];
        float4 rr;
        rr.x = ov.x + xv.x; rr.y = ov.y + xv.y;
        rr.z = ov.z + xv.z; rr.w = ov.w + xv.w;
        *(float4*)&ob[gi] = rr;
    }
}

extern "C" void kernel_launch(void* const* d_in, const int* in_sizes, int n_in,
                              void* d_out, int out_size, void* d_ws, size_t ws_size,
                              hipStream_t stream) {
    const float* x     = (const float*)d_in[0];
    const float* Wq    = (const float*)d_in[1];
    const float* bq    = (const float*)d_in[2];
    const float* Wk    = (const float*)d_in[3];
    const float* bk    = (const float*)d_in[4];
    const float* Wv    = (const float*)d_in[5];
    const float* bv    = (const float*)d_in[6];
    const float* gamma = (const float*)d_in[7];

    const int B = 4;
    __bf16* qT  = (__bf16*)d_ws;                        // 2 MB
    __bf16* kT  = qT + (size_t)B * NPTS * C4DIM;        // 2 MB
    __bf16* v   = kT + (size_t)B * NPTS * C4DIM;        // 8 MB
    __bf16* wsz = v  + (size_t)B * CDIM * NPTS;         // 192 KB bf16 W

    wprep_kernel<<<96, 256, 0, stream>>>(Wq, Wk, Wv, wsz);

    proj_kernel<<<dim3(NPTS/64, 2, B), 256, 0, stream>>>(
        x, bq, bk, bv, wsz, qT, kT, v);

    attn_kernel<<<dim3(NPTS/64, CDIM/128, B), 256, 0, stream>>>(
        qT, kT, v, x, gamma, (float*)d_out);
}